// Round 8
// baseline (397.808 us; speedup 1.0000x reference)
//
#include <hip/hip_runtime.h>
#include <hip/hip_bf16.h>
#include <math.h>

#define NB 8
#define NT 1024
#define ND 768
#define NH 12
#define HD 64
#define WINDOW 768
#define LN_EPS 1e-5f
#define NEGF -3.4028234663852886e38f
#define SCL2 0.18033688011112042f   // 0.125 * log2(e)

static const int BT = NB * NT;  // 8192 rows

typedef __bf16 bf16x8 __attribute__((ext_vector_type(8)));
typedef float  f32x4  __attribute__((ext_vector_type(4)));
typedef unsigned short ushort_t;

__device__ __forceinline__ unsigned short f2bf(float f) {
    __hip_bfloat16 h = __float2bfloat16(f);
    return __builtin_bit_cast(unsigned short, h);
}

// async global->LDS, 16B per lane. LDS dest = wave-uniform base + lane*16.
__device__ __forceinline__ void load_lds16(const void* g, void* l) {
    __builtin_amdgcn_global_load_lds((const __attribute__((address_space(1))) unsigned int*)g,
                                     (__attribute__((address_space(3))) unsigned int*)l,
                                     16, 0, 0);
}

// ---------------- all weight transposes fused: wT[n][k] = bf16(w[k][n]) --------
__global__ __launch_bounds__(256) void transpose_all(const float* __restrict__ w0, ushort_t* __restrict__ t0v,
                                                     const float* __restrict__ w1, ushort_t* __restrict__ t1v,
                                                     const float* __restrict__ w2, ushort_t* __restrict__ t2v,
                                                     const float* __restrict__ w3, ushort_t* __restrict__ t3v) {
    int bid = blockIdx.x;
    const float* w; ushort_t* wt; int K, N;
    if (bid < 1728)                    { w = w0; wt = t0v; K = 768;  N = 2304; }
    else if ((bid -= 1728) < 576)      { w = w1; wt = t1v; K = 768;  N = 768;  }
    else if ((bid -= 576) < 2304)      { w = w2; wt = t2v; K = 768;  N = 3072; }
    else       { bid -= 2304;            w = w3; wt = t3v; K = 3072; N = 768;  }
    const int nxt = N / 32;
    const int n0 = (bid % nxt) * 32, k0 = (bid / nxt) * 32;
    __shared__ float t[32][33];
    const int tx = threadIdx.x & 31, ty = threadIdx.x >> 5;  // 32 x 8
    for (int r = ty; r < 32; r += 8)
        t[r][tx] = w[(size_t)(k0 + r) * N + n0 + tx];
    __syncthreads();
    for (int r = ty; r < 32; r += 8)
        wt[(size_t)(n0 + r) * K + k0 + tx] = f2bf(t[tx][r]);
}

// ---------------- V transpose (pi-permuted keys): vT[b][h][d][t'] --------------
// t' within each 64-block: key' = (key&15)*2 + ((key>>4)&1) + (key&32)
__global__ __launch_bounds__(256) void transpose_v(const ushort_t* __restrict__ qkvb,
                                                   ushort_t* __restrict__ vT) {
    const int t0 = blockIdx.x * 64;
    const int h = blockIdx.y, b = blockIdx.z;
    __shared__ ushort_t sm[64 * 72];
    const int tid = threadIdx.x;
    #pragma unroll
    for (int p = 0; p < 2; p++) {
        int idx = p * 256 + tid;
        int r = idx >> 3, c = idx & 7;
        *(bf16x8*)&sm[r * 72 + c * 8] =
            *(const bf16x8*)(qkvb + (size_t)(b * NT + t0 + r) * (3 * ND) + 2 * ND + h * HD + c * 8);
    }
    __syncthreads();
    #pragma unroll
    for (int p = 0; p < 2; p++) {
        int idx = p * 256 + tid;
        int d = idx >> 3, c2 = idx & 7;
        ushort_t tmp[8];
        #pragma unroll
        for (int j = 0; j < 8; j++) {
            int kp = c2 * 8 + j;
            int key = ((kp & 1) << 4) | ((kp >> 1) & 15) | (kp & 32);
            tmp[j] = sm[key * 72 + d];
        }
        *(bf16x8*)(vT + ((size_t)((b * NH + h) * HD + d)) * NT + t0 + c2 * 8) = *(bf16x8*)tmp;
    }
}

// ---------------- LayerNorm -> bf16: wave-per-row, shuffle reduce --------------
__global__ __launch_bounds__(256) void ln_kernel(const float* __restrict__ x,
                                                 const float* __restrict__ w,
                                                 const float* __restrict__ b,
                                                 ushort_t* __restrict__ out) {
    const int row  = blockIdx.x * 4 + (threadIdx.x >> 6);
    const int lane = threadIdx.x & 63;
    const float* xr = x + (size_t)row * ND;

    float4 v[3];
    #pragma unroll
    for (int s = 0; s < 3; s++) v[s] = *(const float4*)(xr + s * 256 + lane * 4);

    float sum = 0.f;
    #pragma unroll
    for (int s = 0; s < 3; s++) sum += v[s].x + v[s].y + v[s].z + v[s].w;
    #pragma unroll
    for (int off = 1; off < 64; off <<= 1) sum += __shfl_xor(sum, off, 64);
    const float mu = sum * (1.0f / ND);

    float var = 0.f;
    #pragma unroll
    for (int s = 0; s < 3; s++) {
        float a0 = v[s].x - mu, a1 = v[s].y - mu, a2 = v[s].z - mu, a3 = v[s].w - mu;
        var += a0 * a0 + a1 * a1 + a2 * a2 + a3 * a3;
    }
    #pragma unroll
    for (int off = 1; off < 64; off <<= 1) var += __shfl_xor(var, off, 64);
    const float rstd = rsqrtf(var * (1.0f / ND) + LN_EPS);

    #pragma unroll
    for (int s = 0; s < 3; s++) {
        const int col = s * 256 + lane * 4;
        float4 w4 = *(const float4*)(w + col);
        float4 b4 = *(const float4*)(b + col);
        ushort4 r;
        r.x = f2bf((v[s].x - mu) * rstd * w4.x + b4.x);
        r.y = f2bf((v[s].y - mu) * rstd * w4.y + b4.y);
        r.z = f2bf((v[s].z - mu) * rstd * w4.z + b4.z);
        r.w = f2bf((v[s].w - mu) * rstd * w4.w + b4.w);
        *(ushort4*)(out + (size_t)row * ND + col) = r;
    }
}

// ---------------- bf16 MFMA GEMM: multi-tile persistent, cross-tile prefetch ---
// Each block does TPB column-adjacent 128x128 tiles (same bm -> A re-hits L2).
// Flattened (tile, kt) pipeline: last kt of tile t issues tile t+1's chunk 0.
// bf16 epilogue restages via dedicated wave-private LDS (no barrier) so it
// overlaps the next tile's DMA. EPI: 0=+bias bf16; 1=+bias+resid fp32; 2=gelu bf16
template <int EPI, int TPB>
__global__ __launch_bounds__(256) void gemm_bt(const ushort_t* __restrict__ A,
                                               const ushort_t* __restrict__ Bt,
                                               const float* __restrict__ bias,
                                               const float* __restrict__ resid,
                                               void* __restrict__ Cout,
                                               int M, int N, int K, int NCOLP) {
    __shared__ __align__(16) ushort_t smem[2][2][128 * 32];  // [buf][A/B]
    __shared__ __align__(16) ushort_t epi[4][64 * 40];       // bf16 epilogue restage

    const int tid  = threadIdx.x;
    const int bm   = (blockIdx.x / NCOLP) * 128;
    const int bn0  = (blockIdx.x % NCOLP) * (TPB * 128);
    const int lane = tid & 63;
    const int wave = tid >> 6;
    const int wm   = (wave & 1) * 64;
    const int wn   = (wave >> 1) * 64;
    const int fcol = lane & 15;
    const int quad = lane >> 4;

    const int srow = tid >> 2, scg = (tid & 3) * 8;

    auto issue = [&](int bn, int k0, int buf) {
        #pragma unroll
        for (int p = 0; p < 2; p++) {
            const int row = srow + p * 64;
            const int flat = (p * 256 + tid) * 8;
            load_lds16(A  + (size_t)(bm + row) * K + k0 + scg, &smem[buf][0][flat]);
            load_lds16(Bt + (size_t)(bn + row) * K + k0 + scg, &smem[buf][1][flat]);
        }
    };

    const int KT = K >> 5;
    int buf = 0;
    issue(bn0, 0, 0);

    #pragma unroll
    for (int t = 0; t < TPB; t++) {
        const int bn = bn0 + t * 128;
        f32x4 acc[4][4] = {};

        for (int kt = 0; kt < KT; kt++) {
            __syncthreads();
            if (kt + 1 < KT)           issue(bn, (kt + 1) << 5, buf ^ 1);
            else if (t + 1 < TPB)      issue(bn + 128, 0, buf ^ 1);

            bf16x8 a[4], b[4];
            #pragma unroll
            for (int i = 0; i < 4; i++)
                a[i] = *(const bf16x8*)&smem[buf][0][(wm + i * 16 + fcol) * 32 + quad * 8];
            #pragma unroll
            for (int j = 0; j < 4; j++)
                b[j] = *(const bf16x8*)&smem[buf][1][(wn + j * 16 + fcol) * 32 + quad * 8];
            #pragma unroll
            for (int i = 0; i < 4; i++)
                #pragma unroll
                for (int j = 0; j < 4; j++)
                    acc[i][j] = __builtin_amdgcn_mfma_f32_16x16x32_bf16(a[i], b[j], acc[i][j], 0, 0, 0);
            buf ^= 1;
        }

        if (EPI == 1) {
            // fp32 + residual: 16 lanes x 4B = full 64B line per store — direct.
            #pragma unroll
            for (int j = 0; j < 4; j++) {
                const int gcol = bn + wn + j * 16 + fcol;
                const float bs = bias[gcol];
                #pragma unroll
                for (int i = 0; i < 4; i++) {
                    #pragma unroll
                    for (int r = 0; r < 4; r++) {
                        const int grow = bm + wm + i * 16 + quad * 4 + r;
                        float val = acc[i][j][r] + bs + resid[(size_t)grow * N + gcol];
                        ((float*)Cout)[(size_t)grow * N + gcol] = val;
                    }
                }
            }
        } else {
            // bf16 out via wave-private LDS restage -> ushort8 full-line stores.
            ushort_t* Cs = &epi[wave][0];  // 64 rows x (32+8 pad)
            #pragma unroll
            for (int hh = 0; hh < 2; hh++) {
                #pragma unroll
                for (int jj = 0; jj < 2; jj++) {
                    const int j = hh * 2 + jj;
                    const float bs = bias[bn + wn + j * 16 + fcol];
                    #pragma unroll
                    for (int i = 0; i < 4; i++) {
                        #pragma unroll
                        for (int r = 0; r < 4; r++) {
                            float val = acc[i][j][r] + bs;
                            if (EPI == 2) {
                                float y = 0.7978845608028654f * (val + 0.044715f * val * val * val);
                                float tt = 1.0f - 2.0f / (1.0f + __expf(2.0f * y));
                                val = 0.5f * val * (1.0f + tt);
                            }
                            const int lr = i * 16 + quad * 4 + r;
                            Cs[lr * 40 + jj * 16 + fcol] = f2bf(val);
                        }
                    }
                }
                #pragma unroll
                for (int p = 0; p < 4; p++) {
                    const int cid = p * 64 + lane;
                    const int lr = cid >> 2, ck = cid & 3;
                    bf16x8 vv = *(const bf16x8*)&Cs[lr * 40 + ck * 8];
                    *(bf16x8*)((ushort_t*)Cout + (size_t)(bm + wm + lr) * N + bn + wn + hh * 32 + ck * 8) = vv;
                }
            }
        }
    }
}

// ---------------- MFMA flash attention: no-max softmax, l via ones-MFMA --------
__global__ __launch_bounds__(256) void flash_attn_mfma(const ushort_t* __restrict__ qkvb,
                                                       const ushort_t* __restrict__ vT,
                                                       const int* __restrict__ amask,
                                                       ushort_t* __restrict__ out) {
    const int qt = 15 - blockIdx.x;   // heavy tiles first
    const int h  = blockIdx.y;
    const int b  = blockIdx.z;
    const int q0 = qt * 64;

    __shared__ __align__(16) ushort_t QPs[64 * 64];      // Q, then reused for P
    __shared__ __align__(16) ushort_t Ks[2][64 * 64];
    __shared__ __align__(16) ushort_t Vts[2][64 * 64];

    const int tid  = threadIdx.x;
    const int lane = tid & 63;
    const int wave = tid >> 6;
    const int fcol = lane & 15;
    const int quad = lane >> 4;
    const int wq0  = wave * 16;

    #pragma unroll
    for (int p = 0; p < 2; p++) {
        int flat = p * 256 + tid;
        int r = flat >> 3, c = (flat & 7) ^ (r & 7);
        load_lds16(qkvb + (size_t)(b * NT + q0 + r) * (3 * ND) + h * HD + c * 8, &QPs[flat * 8]);
    }
    __syncthreads();

    bf16x8 aQ[2];
    {
        const int qr = wq0 + fcol;
        #pragma unroll
        for (int ks = 0; ks < 2; ks++) {
            int c = ks * 4 + quad;
            aQ[ks] = *(const bf16x8*)&QPs[qr * 64 + ((c ^ (qr & 7)) * 8)];
        }
    }
    // QPs rows are per-wave-private from here on.

    bf16x8 bones;
    #pragma unroll
    for (int i = 0; i < 8; i++) bones[i] = (__bf16)1.0f;

    auto issueKV = [&](int cch, int buf) {
        const int kbase = cch * 64;
        #pragma unroll
        for (int p = 0; p < 2; p++) {
            int flat = p * 256 + tid;
            int r = flat >> 3, c = (flat & 7) ^ (r & 7);
            load_lds16(qkvb + (size_t)(b * NT + kbase + r) * (3 * ND) + ND + h * HD + c * 8,
                       &Ks[buf][flat * 8]);
            load_lds16(vT + ((size_t)((b * NH + h) * HD + r)) * NT + kbase + c * 8,
                       &Vts[buf][flat * 8]);
        }
    };

    f32x4 oacc[4] = {};
    f32x4 lacc = {};

    const int c_lo = (qt > 12) ? (qt - 12) : 0;
    issueKV(c_lo, 0);
    for (int cch = c_lo; cch <= qt; cch++) {
        const int cur = (cch - c_lo) & 1;
        const int kbase = cch * 64;
        __syncthreads();
        if (cch + 1 <= qt) issueKV(cch + 1, cur ^ 1);

        int am[4];
        #pragma unroll
        for (int jn = 0; jn < 4; jn++) am[jn] = amask[b * NT + kbase + jn * 16 + fcol];
        const int amok_lane = (am[0] != 0) & (am[1] != 0) & (am[2] != 0) & (am[3] != 0);
        const bool fast = (cch < qt) && (cch >= qt - 11) && __all(amok_lane);

        f32x4 sc[4] = {};
        #pragma unroll
        for (int ks = 0; ks < 2; ks++) {
            #pragma unroll
            for (int jn = 0; jn < 4; jn++) {
                const int kr = jn * 16 + fcol;
                bf16x8 bk = *(const bf16x8*)&Ks[cur][kr * 64 + (((ks * 4 + quad) ^ (kr & 7)) * 8)];
                sc[jn] = __builtin_amdgcn_mfma_f32_16x16x32_bf16(aQ[ks], bk, sc[jn], 0, 0, 0);
            }
        }

        float pvv[4][4];
        if (fast) {
            #pragma unroll
            for (int jn = 0; jn < 4; jn++)
                #pragma unroll
                for (int r = 0; r < 4; r++)
                    pvv[jn][r] = __builtin_amdgcn_exp2f(sc[jn][r] * SCL2);
        } else {
            #pragma unroll
            for (int jn = 0; jn < 4; jn++) {
                const int jg = kbase + jn * 16 + fcol;
                const bool amok = (am[jn] != 0);
                #pragma unroll
                for (int r = 0; r < 4; r++) {
                    const int ig = q0 + wq0 + quad * 4 + r;
                    bool keep = (jg <= ig) && (jg >= ig - (WINDOW - 1)) && amok;
                    float s = keep ? sc[jn][r] * SCL2 : -1e38f;
                    pvv[jn][r] = __builtin_amdgcn_exp2f(s);
                }
            }
        }

        // P -> LDS, pi-permuted packed pairs
        #pragma unroll
        for (int half = 0; half < 2; half++) {
            const int cbase = half * 4 + (fcol >> 2);
            const int off = (fcol & 3) * 2;
            #pragma unroll
            for (int r = 0; r < 4; r++) {
                const int row = wq0 + quad * 4 + r;
                unsigned int pk = (unsigned int)f2bf(pvv[half * 2][r]) |
                                  ((unsigned int)f2bf(pvv[half * 2 + 1][r]) << 16);
                *(unsigned int*)&QPs[row * 64 + ((cbase ^ (row & 7)) * 8) + off] = pk;
            }
        }

        // O += P @ V^T (permuted k axis); l += P @ ones
        #pragma unroll
        for (int ks = 0; ks < 2; ks++) {
            const int pr = wq0 + fcol;
            bf16x8 ap = *(const bf16x8*)&QPs[pr * 64 + (((ks * 4 + quad) ^ (pr & 7)) * 8)];
            lacc = __builtin_amdgcn_mfma_f32_16x16x32_bf16(ap, bones, lacc, 0, 0, 0);
            #pragma unroll
            for (int jd = 0; jd < 4; jd++) {
                const int vr = jd * 16 + fcol;
                bf16x8 bv = *(const bf16x8*)&Vts[cur][vr * 64 + (((ks * 4 + quad) ^ (vr & 7)) * 8)];
                oacc[jd] = __builtin_amdgcn_mfma_f32_16x16x32_bf16(ap, bv, oacc[jd], 0, 0, 0);
            }
        }
    }

    #pragma unroll
    for (int r = 0; r < 4; r++) {
        const float inv = 1.0f / lacc[r];
        const size_t row = (size_t)(b * NT + q0 + wq0 + quad * 4 + r);
        #pragma unroll
        for (int jd = 0; jd < 4; jd++)
            out[row * ND + h * HD + jd * 16 + fcol] = f2bf(oacc[jd][r] * inv);
    }
}

extern "C" void kernel_launch(void* const* d_in, const int* in_sizes, int n_in,
                              void* d_out, int out_size, void* d_ws, size_t ws_size,
                              hipStream_t stream) {
    const float* x        = (const float*)d_in[0];
    const int*   amask    = (const int*)  d_in[1];
    const float* ln1_w    = (const float*)d_in[2];
    const float* ln1_b    = (const float*)d_in[3];
    const float* w_attn   = (const float*)d_in[4];
    const float* b_attn   = (const float*)d_in[5];
    const float* w_proj   = (const float*)d_in[6];
    const float* b_proj   = (const float*)d_in[7];
    const float* ln2_w    = (const float*)d_in[8];
    const float* ln2_b    = (const float*)d_in[9];
    const float* w_fc     = (const float*)d_in[10];
    const float* b_fc     = (const float*)d_in[11];
    const float* w_fcp    = (const float*)d_in[12];
    const float* b_fcp    = (const float*)d_in[13];
    float* out = (float*)d_out;

    ushort_t* ws = (ushort_t*)d_ws;
    ushort_t* qkvb   = ws;                               // BT*3*ND
    ushort_t* x1b    = qkvb + (size_t)BT * 3 * ND;       // BT*ND
    ushort_t* attn_b = x1b + (size_t)BT * ND;            // BT*ND
    ushort_t* hbuf   = attn_b + (size_t)BT * ND;         // BT*4*ND
    ushort_t* vTb    = hbuf + (size_t)BT * 4 * ND;       // BT*ND
    ushort_t* wA_T   = vTb + (size_t)BT * ND;            // 2304*768
    ushort_t* wP_T   = wA_T + (size_t)2304 * 768;        // 768*768
    ushort_t* wF_T   = wP_T + (size_t)768 * 768;         // 3072*768
    ushort_t* wFP_T  = wF_T + (size_t)3072 * 768;        // 768*3072

    transpose_all<<<6912, 256, 0, stream>>>(w_attn, wA_T, w_proj, wP_T, w_fc, wF_T, w_fcp, wFP_T);

    ln_kernel<<<BT / 4, 256, 0, stream>>>(x, ln1_w, ln1_b, x1b);
    // qkv: N=2304 -> 18 col tiles, TPB=2 -> NCOLP=9, grid 576
    gemm_bt<0, 2><<<64 * 9, 256, 0, stream>>>(x1b, wA_T, b_attn, nullptr, qkvb, BT, 3 * ND, ND, 9);
    transpose_v<<<dim3(16, NH, NB), 256, 0, stream>>>(qkvb, vTb);
    flash_attn_mfma<<<dim3(16, NH, NB), 256, 0, stream>>>(qkvb, vTb, amask, attn_b);
    // proj: N=768 -> 6 col tiles, TPB=1, grid 384
    gemm_bt<1, 1><<<64 * 6, 256, 0, stream>>>(attn_b, wP_T, b_proj, x, out, BT, ND, ND, 6);
    ln_kernel<<<BT / 4, 256, 0, stream>>>(out, ln2_w, ln2_b, x1b);
    // fc: N=3072 -> 24 col tiles, TPB=2 -> NCOLP=12, grid 768 (exactly 3/CU)
    gemm_bt<2, 2><<<64 * 12, 256, 0, stream>>>(x1b, wF_T, b_fc, nullptr, hbuf, BT, 4 * ND, ND, 12);
    // fc_proj: N=768, K=3072, TPB=1, grid 384
    gemm_bt<1, 1><<<64 * 6, 256, 0, stream>>>(hbuf, wFP_T, b_fcp, out, out, BT, ND, 4 * ND, 6);
}